// Round 7
// baseline (1623.932 us; speedup 1.0000x reference)
//
#include <hip/hip_runtime.h>
#include <math.h>

// LSTM: B=512, T=1000, I=64, H=50, gates 4H=200 (torch order i,f,g,o).
//
// ROUND-7 STRUCTURE: barrier-free recurrence.
// R4/R5/R6 all shared one flaw: gates split across lanes => h scattered
// across 4 waves => every step pays LDS+s_barrier broadcast (~1650cyc step,
// VALUBusy 44%). R7 transposes the decomposition: ONE LANE OWNS ONE UNIT u
// and computes all 4 of u's gates (4x50 dots, W_hh 4 rows = 200 VGPRs/lane).
// h then lives in 50 lanes of ONE wave: h write->read is same-wave LDS,
// ordered by lgkmcnt ONLY -- no barrier in the recurrence chain. The step
// barrier survives only to rotate the x/xg rings (2-step slack), and the
// consumer arrives at it last => ~free.
//
// Block = 256 threads = 4 waves, one batch row; grid = B = 512 (2 blocks/CU).
// Logical roles (rotated by blockIdx so co-resident blocks' consumers land
// on different SIMDs):
//   lw 0: CONSUMER (lanes 0..49 = unit u). Per step: 4 xg reads + 13
//         broadcast ds_read_b128 of h + 104 pk-FMA (4 independent chains) +
//         4 independent exps + c/tanh + h write.
//   lw 1,2: PRODUCERS (pid 0..127; gates k=pid and k=pid+128 if <200).
//         xg[s+2] = bias + x[s+2].W_ih from x ring -> xg ring.
//   lw 3: LOADER (lanes 0..31). Depth-4 x prefetch (write x[s+3], load
//         x[s+7]) across raw lgkmcnt-only barriers.

#define HSZ 50
#define ISZ 64
#define TSZ 1000

typedef float f32x2 __attribute__((ext_vector_type(2)));

// One step, s = t+OFF, OFF compile-time in {0,1,2,3}; t%4==0 -> s&3==OFF.
#define LSTM_STEP(t, OFF, XR)                                                  \
  {                                                                            \
    if (lw == 0) {                                                             \
      if (lane < HSZ) {                                                        \
        /* xg reads first: latency hides under h reads/FMA stream */           \
        float xgi = xgring[(OFF) & 3][lane];                                   \
        float xgf = xgring[(OFF) & 3][HSZ + lane];                             \
        float xgg = xgring[(OFF) & 3][2 * HSZ + lane];                         \
        float xgo = xgring[(OFF) & 3][3 * HSZ + lane];                         \
        f32x2 acc0; acc0.x = xgi; acc0.y = 0.0f;                               \
        f32x2 acc1; acc1.x = xgf; acc1.y = 0.0f;                               \
        f32x2 acc2; acc2.x = xgg; acc2.y = 0.0f;                               \
        f32x2 acc3; acc3.x = xgo; acc3.y = 0.0f;                               \
        const float4* h4 = (const float4*)(&hbuf[(OFF) & 1][0]);               \
        _Pragma("unroll")                                                      \
        for (int j = 0; j < 12; ++j) {                                         \
          float4 v = h4[j];                                                    \
          f32x2 lo; lo.x = v.x; lo.y = v.y;                                    \
          f32x2 hi; hi.x = v.z; hi.y = v.w;                                    \
          acc0 += lo * wreg[2 * j];          acc0 += hi * wreg[2 * j + 1];     \
          acc1 += lo * wreg[25 + 2 * j];     acc1 += hi * wreg[25 + 2 * j + 1];\
          acc2 += lo * wreg[50 + 2 * j];     acc2 += hi * wreg[50 + 2 * j + 1];\
          acc3 += lo * wreg[75 + 2 * j];     acc3 += hi * wreg[75 + 2 * j + 1];\
        }                                                                      \
        { f32x2 tl = *(const f32x2*)(&hbuf[(OFF) & 1][48]);                    \
          acc0 += tl * wreg[24]; acc1 += tl * wreg[49];                        \
          acc2 += tl * wreg[74]; acc3 += tl * wreg[99]; }                      \
        float s0 = acc0.x + acc0.y, s1 = acc1.x + acc1.y;                      \
        float s2 = acc2.x + acc2.y, s3 = acc3.x + acc3.y;                      \
        /* 4 independent activations: i,f,o sigmoid; g tanh=2sig(2v)-1 */      \
        float e0 = __expf(-s0), e1 = __expf(-s1);                              \
        float e2 = __expf(-2.0f * s2), e3 = __expf(-s3);                       \
        float i_ = __builtin_amdgcn_rcpf(1.0f + e0);                           \
        float f_ = __builtin_amdgcn_rcpf(1.0f + e1);                           \
        float g_ = __builtin_fmaf(2.0f, __builtin_amdgcn_rcpf(1.0f + e2),      \
                                  -1.0f);                                      \
        float o_ = __builtin_amdgcn_rcpf(1.0f + e3);                           \
        c_reg = __builtin_fmaf(f_, c_reg, i_ * g_);                            \
        float ec = __expf(2.0f * c_reg);                                       \
        float rr = __builtin_amdgcn_rcpf(1.0f + ec);                           \
        float hv = o_ * __builtin_fmaf(-2.0f, rr, 1.0f);   /* o*tanh(c) */     \
        hbuf[((OFF) + 1) & 1][lane] = hv;                                      \
      }                                                                        \
    } else if (lw <= 2) {                                                      \
      if ((t) + (OFF) + 2 < TSZ) {                                             \
        const float4* x4 = (const float4*)(&xring[((OFF) + 2) & 3][0]);        \
        f32x2 a1; a1.x = bias0; a1.y = 0.0f;                                   \
        f32x2 b1; b1.x = 0.0f; b1.y = 0.0f;                                    \
        f32x2 a2; a2.x = bias1; a2.y = 0.0f;                                   \
        f32x2 b2; b2.x = 0.0f; b2.y = 0.0f;                                    \
        _Pragma("unroll")                                                      \
        for (int i = 0; i < 16; ++i) {                                         \
          float4 v = x4[i];                                                    \
          f32x2 lo; lo.x = v.x; lo.y = v.y;                                    \
          f32x2 hi; hi.x = v.z; hi.y = v.w;                                    \
          a1 += lo * wreg[2 * i];      b1 += hi * wreg[2 * i + 1];             \
          a2 += lo * wreg[32 + 2 * i]; b2 += hi * wreg[32 + 2 * i + 1];        \
        }                                                                      \
        xgring[((OFF) + 2) & 3][k1] = (a1.x + b1.x) + (a1.y + b1.y);           \
        if (pid < 72)                                                          \
          xgring[((OFF) + 2) & 3][k1 + 128] = (a2.x + b2.x) + (a2.y + b2.y);   \
      }                                                                        \
    } else if (lane < 32) {                                                    \
      if ((t) + (OFF) + 3 < TSZ)                                               \
        *(f32x2*)(&xring[((OFF) + 3) & 3][2 * lane]) = XR;                     \
      if ((t) + (OFF) + 7 < TSZ)                                               \
        XR = *(const f32x2*)(xrow + (size_t)((t) + (OFF) + 7) * ISZ + 2*lane); \
    }                                                                          \
    /* ring rotation only; consumer's h never crosses this barrier */          \
    asm volatile("s_waitcnt lgkmcnt(0)" ::: "memory");                         \
    __builtin_amdgcn_s_barrier();                                              \
    __builtin_amdgcn_sched_barrier(0);                                         \
  }

__global__ __launch_bounds__(256, 2) void lstm_fused(
    const float* __restrict__ x,      // [B, T, I]
    const float* __restrict__ W_ih,   // [4H, I]
    const float* __restrict__ W_hh,   // [4H, H]
    const float* __restrict__ b_ih,   // [4H]
    const float* __restrict__ b_hh,   // [4H]
    const float* __restrict__ W_out,  // [2, H]
    const float* __restrict__ b_out,  // [2]
    float* __restrict__ out)          // [B, 2]
{
    const int row  = blockIdx.x;      // one batch row per block
    const int tid  = threadIdx.x;
    const int lane = tid & 63;
    const int pw   = tid >> 6;                      // physical wave 0..3
    const int rot  = (row + (row >> 8)) & 3;        // co-resident blocks differ
    const int lw   = (pw + rot) & 3;                // logical role

    __shared__ __align__(16) float xring[4][ISZ];    // 1 KiB
    __shared__ __align__(16) float xgring[4][200];   // 3.2 KiB
    __shared__ __align__(16) float hbuf[2][52];      // ping-pong h

    const float* xrow = x + (size_t)row * (TSZ * ISZ);

    // UNIONED weight registers:
    //   consumer: wreg[g*25 + p] = W_hh[g*50+lane] pair p   (100 f32x2)
    //   producer: wreg[0..31] row k1, wreg[32..63] row k2    (64 f32x2)
    f32x2 wreg[100];
    float bias0 = 0.0f, bias1 = 0.0f;
    float c_reg = 0.0f;
    f32x2 xr0; xr0.x = 0.0f; xr0.y = 0.0f;
    f32x2 xr1; xr1.x = 0.0f; xr1.y = 0.0f;
    f32x2 xr2; xr2.x = 0.0f; xr2.y = 0.0f;
    f32x2 xr3; xr3.x = 0.0f; xr3.y = 0.0f;
    int pid = 0, k1 = 0;

    if (lw == 0) {
        if (lane < HSZ) {
            #pragma unroll
            for (int g = 0; g < 4; ++g) {
                const float* wh = W_hh + (g * HSZ + lane) * HSZ;  // row, 50 f
                #pragma unroll
                for (int p = 0; p < 25; ++p)
                    wreg[g * 25 + p] = *(const f32x2*)(wh + 2 * p);
            }
        }
    } else if (lw <= 2) {
        pid = (lw - 1) * 64 + lane;     // 0..127
        k1  = pid;
        const float* wi = W_ih + (size_t)k1 * ISZ;
        #pragma unroll
        for (int i = 0; i < 32; ++i) wreg[i] = *(const f32x2*)(wi + 2 * i);
        bias0 = b_ih[k1] + b_hh[k1];
        if (pid < 72) {
            const float* wi2 = W_ih + (size_t)(k1 + 128) * ISZ;
            #pragma unroll
            for (int i = 0; i < 32; ++i)
                wreg[32 + i] = *(const f32x2*)(wi2 + 2 * i);
            bias1 = b_ih[k1 + 128] + b_hh[k1 + 128];
        } else {
            #pragma unroll
            for (int i = 0; i < 32; ++i) {
                wreg[32 + i].x = 0.0f; wreg[32 + i].y = 0.0f;
            }
        }
    } else if (lane < 32) {
        // loader: stage x[0..2]; preload regs with x[3..6]
        #pragma unroll
        for (int n = 0; n < 3; ++n)
            *(f32x2*)(&xring[n][2 * lane]) =
                *(const f32x2*)(xrow + (size_t)n * ISZ + 2 * lane);
        xr0 = *(const f32x2*)(xrow + 3 * (size_t)ISZ + 2 * lane);
        xr1 = *(const f32x2*)(xrow + 4 * (size_t)ISZ + 2 * lane);
        xr2 = *(const f32x2*)(xrow + 5 * (size_t)ISZ + 2 * lane);
        xr3 = *(const f32x2*)(xrow + 6 * (size_t)ISZ + 2 * lane);
    }
    if (tid < 52) { hbuf[0][tid] = 0.0f; hbuf[1][tid] = 0.0f; }
    __syncthreads();

    // producer prologue: xg[0] and xg[1] into ring slots 0,1
    if (lw == 1 || lw == 2) {
        #pragma unroll
        for (int n = 0; n < 2; ++n) {
            const float4* x4 = (const float4*)(&xring[n][0]);
            f32x2 a1; a1.x = bias0; a1.y = 0.0f;
            f32x2 b1; b1.x = 0.0f; b1.y = 0.0f;
            f32x2 a2; a2.x = bias1; a2.y = 0.0f;
            f32x2 b2; b2.x = 0.0f; b2.y = 0.0f;
            #pragma unroll
            for (int i = 0; i < 16; ++i) {
                float4 v = x4[i];
                f32x2 lo; lo.x = v.x; lo.y = v.y;
                f32x2 hi; hi.x = v.z; hi.y = v.w;
                a1 += lo * wreg[2 * i];      b1 += hi * wreg[2 * i + 1];
                a2 += lo * wreg[32 + 2 * i]; b2 += hi * wreg[32 + 2 * i + 1];
            }
            xgring[n][k1] = (a1.x + b1.x) + (a1.y + b1.y);
            if (pid < 72)
                xgring[n][k1 + 128] = (a2.x + b2.x) + (a2.y + b2.y);
        }
    }
    __syncthreads();

    for (int t = 0; t < TSZ; t += 4) {
        LSTM_STEP(t, 0, xr0)
        LSTM_STEP(t, 1, xr1)
        LSTM_STEP(t, 2, xr2)
        LSTM_STEP(t, 3, xr3)
    }
    // last step (s=999, OFF=3) wrote h_final into hbuf[0]; its lgkmcnt(0)
    // + s_barrier makes it visible to all waves.

    if (tid < 2) {
        float acc = b_out[tid];
        const float* wo = W_out + tid * HSZ;
        #pragma unroll
        for (int j = 0; j < HSZ; ++j) acc += hbuf[0][j] * wo[j];
        out[row * 2 + tid] = acc;
    }
}

extern "C" void kernel_launch(void* const* d_in, const int* in_sizes, int n_in,
                              void* d_out, int out_size, void* d_ws, size_t ws_size,
                              hipStream_t stream) {
    const float* x     = (const float*)d_in[0];
    const float* W_ih  = (const float*)d_in[1];
    const float* W_hh  = (const float*)d_in[2];
    const float* b_ih  = (const float*)d_in[3];
    const float* b_hh  = (const float*)d_in[4];
    const float* W_out = (const float*)d_in[5];
    const float* b_out = (const float*)d_in[6];
    float* out = (float*)d_out;

    const int B = in_sizes[0] / (TSZ * ISZ);   // 512
    hipLaunchKernelGGL(lstm_fused, dim3(B), dim3(256), 0, stream,
                       x, W_ih, W_hh, b_ih, b_hh, W_out, b_out, out);
}

// Round 8
// 995.470 us; speedup vs baseline: 1.6313x; 1.6313x over previous
//
#include <hip/hip_runtime.h>
#include <math.h>

// LSTM: B=512, T=1000, I=64, H=50, gates 4H=200 (torch order i,f,g,o).
//
// ROUND-8: R7's barrier-free recurrence, with a register budget that fits.
// R7 spilled (needed ~240 regs at a 128 cap -> 24GB scratch traffic). R8:
// block = 256 thr = 4 waves = EXACTLY 1 wave/SIMD (launch_bounds(256,1),
// cap 256+ arch VGPRs), grid 256 = 1 block/CU, TWO rows per block:
//   wave 0: consumer row 0. lane u<50 owns unit u: all 4 gates, W_hh rows
//           {u,50+u,100+u,150+u} = 100 f32x2 in VGPRs. Per step: 1 b128 xg
//           read + 13 LDS broadcast reads of h + 100 pk-FMA (4 indep chains)
//           + activations + c update + 1 h write. h write->read is SAME-WAVE
//           (lgkmcnt-ordered): NO barrier in the recurrence chain, and the
//           wave is ALONE on its SIMD (no issue contention).
//   wave 1: consumer row 1.
//   wave 2: producer gates {i,f} for BOTH rows (lane u: W_ih rows u,50+u =
//           64 f32x2 -- 2 gates/lane keeps producer frame << consumer's).
//           Lanes 50..57: depth-4 x loader for row 0.
//   wave 3: producer gates {g,o}; lanes 50..57: loader row 1.
// Barrier only EVERY 2 STEPS (ring rotation; 4-deep rings; within a window
// consumer reads slots s,s+1 while producers write s+2,s+3 and loaders write
// x slot s&3 -- all disjoint; every cross-role handoff crosses a barrier).

#define HSZ 50
#define ISZ 64
#define TSZ 1000

typedef float f32x2 __attribute__((ext_vector_type(2)));

__device__ __forceinline__ float rcp_(float v) {
    return __builtin_amdgcn_rcpf(v);
}

// ---- consumer: one step for row ROW (= wv, runtime; LDS addr only) ----
#define CONSUME(ROW, OFF)                                                      \
  {                                                                            \
    float4 xg4 = *(const float4*)(&xgring[ROW][(OFF) & 3][lane][0]);           \
    f32x2 a0; a0.x = xg4.x; a0.y = 0.0f;                                       \
    f32x2 a1; a1.x = xg4.y; a1.y = 0.0f;                                       \
    f32x2 a2; a2.x = xg4.z; a2.y = 0.0f;                                       \
    f32x2 a3; a3.x = xg4.w; a3.y = 0.0f;                                       \
    const float4* h4 = (const float4*)(&hbuf[ROW][(OFF) & 1][0]);              \
    _Pragma("unroll")                                                          \
    for (int j = 0; j < 12; ++j) {                                             \
      float4 v = h4[j];                                                        \
      f32x2 lo; lo.x = v.x; lo.y = v.y;                                        \
      f32x2 hi; hi.x = v.z; hi.y = v.w;                                        \
      a0 += lo * wreg[2 * j];      a0 += hi * wreg[2 * j + 1];                 \
      a1 += lo * wreg[25 + 2 * j]; a1 += hi * wreg[25 + 2 * j + 1];            \
      a2 += lo * wreg[50 + 2 * j]; a2 += hi * wreg[50 + 2 * j + 1];            \
      a3 += lo * wreg[75 + 2 * j]; a3 += hi * wreg[75 + 2 * j + 1];            \
    }                                                                          \
    { f32x2 tl = *(const f32x2*)(&hbuf[ROW][(OFF) & 1][48]);                   \
      a0 += tl * wreg[24]; a1 += tl * wreg[49];                                \
      a2 += tl * wreg[74]; a3 += tl * wreg[99]; }                              \
    float s0 = a0.x + a0.y, s1 = a1.x + a1.y;                                  \
    float s2 = a2.x + a2.y, s3 = a3.x + a3.y;                                  \
    float e0 = __expf(-s0), e1 = __expf(-s1);                                  \
    float e2 = __expf(-2.0f * s2), e3 = __expf(-s3);                           \
    float i_ = rcp_(1.0f + e0);                                                \
    float f_ = rcp_(1.0f + e1);                                                \
    float g_ = __builtin_fmaf(2.0f, rcp_(1.0f + e2), -1.0f);                   \
    float o_ = rcp_(1.0f + e3);                                                \
    c_reg = __builtin_fmaf(f_, c_reg, i_ * g_);                                \
    float ec = __expf(2.0f * c_reg);                                           \
    float rr = rcp_(1.0f + ec);                                                \
    float hv = o_ * __builtin_fmaf(-2.0f, rr, 1.0f);  /* o * tanh(c) */        \
    hbuf[ROW][((OFF) + 1) & 1][lane] = hv;                                     \
  }

// ---- producer: xg[s+2] for both rows, gates gb,gb+1 of unit `lane` ----
#define PRODUCE(t, OFF)                                                        \
  if ((t) + (OFF) + 2 < TSZ) {                                                 \
    const float4* x0 = (const float4*)(&xring[0][((OFF) + 2) & 3][0]);         \
    const float4* x1 = (const float4*)(&xring[1][((OFF) + 2) & 3][0]);         \
    f32x2 pa0; pa0.x = biasA; pa0.y = 0.0f;                                    \
    f32x2 pb0; pb0.x = biasB; pb0.y = 0.0f;                                    \
    f32x2 pa1; pa1.x = biasA; pa1.y = 0.0f;                                    \
    f32x2 pb1; pb1.x = biasB; pb1.y = 0.0f;                                    \
    _Pragma("unroll")                                                          \
    for (int i = 0; i < 16; ++i) {                                             \
      float4 v0 = x0[i]; float4 v1 = x1[i];                                    \
      f32x2 lo0; lo0.x = v0.x; lo0.y = v0.y;                                   \
      f32x2 hi0; hi0.x = v0.z; hi0.y = v0.w;                                   \
      f32x2 lo1; lo1.x = v1.x; lo1.y = v1.y;                                   \
      f32x2 hi1; hi1.x = v1.z; hi1.y = v1.w;                                   \
      pa0 += lo0 * wreg[2 * i];      pa0 += hi0 * wreg[2 * i + 1];             \
      pb0 += lo0 * wreg[32 + 2 * i]; pb0 += hi0 * wreg[32 + 2 * i + 1];        \
      pa1 += lo1 * wreg[2 * i];      pa1 += hi1 * wreg[2 * i + 1];             \
      pb1 += lo1 * wreg[32 + 2 * i]; pb1 += hi1 * wreg[32 + 2 * i + 1];        \
    }                                                                          \
    f32x2 r0; r0.x = pa0.x + pa0.y; r0.y = pb0.x + pb0.y;                      \
    f32x2 r1; r1.x = pa1.x + pa1.y; r1.y = pb1.x + pb1.y;                      \
    *(f32x2*)(&xgring[0][((OFF) + 2) & 3][lane][gb]) = r0;                     \
    *(f32x2*)(&xgring[1][((OFF) + 2) & 3][lane][gb]) = r1;                     \
  }

// ---- loader (producer-wave lanes 50..57): write x[s+4], load x[s+8] ----
#define LOAD(t, OFF, XA, XB)                                                   \
  {                                                                            \
    if ((t) + (OFF) + 4 < TSZ) {                                               \
      *(float4*)(&xring[lr][(OFF) & 3][8 * lj])     = XA;                      \
      *(float4*)(&xring[lr][(OFF) & 3][8 * lj + 4]) = XB;                      \
    }                                                                          \
    if ((t) + (OFF) + 8 < TSZ) {                                               \
      XA = *(const float4*)(xrowL + (size_t)((t)+(OFF)+8) * ISZ + 8 * lj);     \
      XB = *(const float4*)(xrowL + (size_t)((t)+(OFF)+8) * ISZ + 8 * lj + 4); \
    }                                                                          \
  }

#define LSTM_STEP(t, OFF, XA, XB)                                              \
  {                                                                            \
    if (wv < 2) {                                                              \
      if (lane < HSZ) CONSUME(wv, OFF)                                         \
    } else if (lane < HSZ) {                                                   \
      PRODUCE(t, OFF)                                                          \
    } else if (lane < 58) {                                                    \
      LOAD(t, OFF, XA, XB)                                                     \
    }                                                                          \
  }

#define WINDOW_BARRIER                                                         \
    asm volatile("s_waitcnt lgkmcnt(0)" ::: "memory");                         \
    __builtin_amdgcn_s_barrier();                                              \
    __builtin_amdgcn_sched_barrier(0);

__global__ __launch_bounds__(256, 1) void lstm_fused(
    const float* __restrict__ x,      // [B, T, I]
    const float* __restrict__ W_ih,   // [4H, I]
    const float* __restrict__ W_hh,   // [4H, H]
    const float* __restrict__ b_ih,   // [4H]
    const float* __restrict__ b_hh,   // [4H]
    const float* __restrict__ W_out,  // [2, H]
    const float* __restrict__ b_out,  // [2]
    float* __restrict__ out)          // [B, 2]
{
    const int bb   = blockIdx.x;
    const int tid  = threadIdx.x;
    const int wv   = tid >> 6;        // wave 0..3 (one per SIMD)
    const int lane = tid & 63;

    __shared__ __align__(16) float xring[2][4][ISZ];      // x, per row (2 KiB)
    __shared__ __align__(16) float xgring[2][4][HSZ][4];  // xg [u][g] (6.4 KiB)
    __shared__ __align__(16) float hbuf[2][2][52];        // h ping-pong per row

    // UNIONED weights: consumers wreg[0..99] = W_hh rows {g*50+lane};
    // producers wreg[0..63] = W_ih rows {gb*50+lane, (gb+1)*50+lane}.
    f32x2 wreg[100];
    float biasA = 0.0f, biasB = 0.0f;
    float c_reg = 0.0f;
    float4 xa0{}, xa1{}, xa2{}, xa3{};   // loader in-flight (first 4 floats)
    float4 xb0{}, xb1{}, xb2{}, xb3{};   // loader in-flight (second 4 floats)

    const int gb = (wv - 2) * 2;         // producer gate base (0 or 2)
    const int lr = wv - 2;               // loader row (0 or 1)
    const int lj = lane - 50;            // loader sub-lane 0..7
    const float* xrowL = x + (size_t)(2 * bb + lr) * (TSZ * ISZ);

    if (wv < 2) {
        if (lane < HSZ) {
            #pragma unroll
            for (int g = 0; g < 4; ++g) {
                const float* wh = W_hh + (g * HSZ + lane) * HSZ;
                #pragma unroll
                for (int p = 0; p < 25; ++p)
                    wreg[g * 25 + p] = *(const f32x2*)(wh + 2 * p);
            }
        }
    } else if (lane < HSZ) {
        const int kA = gb * HSZ + lane, kB = (gb + 1) * HSZ + lane;
        const float* wiA = W_ih + (size_t)kA * ISZ;
        const float* wiB = W_ih + (size_t)kB * ISZ;
        #pragma unroll
        for (int i = 0; i < 32; ++i) {
            wreg[i]      = *(const f32x2*)(wiA + 2 * i);
            wreg[32 + i] = *(const f32x2*)(wiB + 2 * i);
        }
        biasA = b_ih[kA] + b_hh[kA];
        biasB = b_ih[kB] + b_hh[kB];
    } else if (lane < 58) {
        // stage x[0..3] into ring slots 0..3; preload regs with x[4..7]
        #pragma unroll
        for (int n = 0; n < 4; ++n) {
            *(float4*)(&xring[lr][n][8 * lj]) =
                *(const float4*)(xrowL + (size_t)n * ISZ + 8 * lj);
            *(float4*)(&xring[lr][n][8 * lj + 4]) =
                *(const float4*)(xrowL + (size_t)n * ISZ + 8 * lj + 4);
        }
        xa0 = *(const float4*)(xrowL + 4 * (size_t)ISZ + 8 * lj);
        xb0 = *(const float4*)(xrowL + 4 * (size_t)ISZ + 8 * lj + 4);
        xa1 = *(const float4*)(xrowL + 5 * (size_t)ISZ + 8 * lj);
        xb1 = *(const float4*)(xrowL + 5 * (size_t)ISZ + 8 * lj + 4);
        xa2 = *(const float4*)(xrowL + 6 * (size_t)ISZ + 8 * lj);
        xb2 = *(const float4*)(xrowL + 6 * (size_t)ISZ + 8 * lj + 4);
        xa3 = *(const float4*)(xrowL + 7 * (size_t)ISZ + 8 * lj);
        xb3 = *(const float4*)(xrowL + 7 * (size_t)ISZ + 8 * lj + 4);
    }
    if (tid < 52) { hbuf[0][0][tid] = 0.0f; hbuf[1][0][tid] = 0.0f; }
    __syncthreads();

    // producer prologue: xg[0], xg[1] into slots 0,1 (consumed at steps 0,1)
    if (wv >= 2 && lane < HSZ) {
        #pragma unroll
        for (int n = 0; n < 2; ++n) {
            PRODUCE(n - 2, 0)          // (t+OFF+2) == n: reads x slot n
        }
    }
    __syncthreads();

    for (int t = 0; t < TSZ; t += 4) {
        LSTM_STEP(t, 0, xa0, xb0)
        LSTM_STEP(t, 1, xa1, xb1)
        WINDOW_BARRIER
        LSTM_STEP(t, 2, xa2, xb2)
        LSTM_STEP(t, 3, xa3, xb3)
        WINDOW_BARRIER
    }
    // after step 999 (odd), h_final sits in hbuf[row][0]; consumer reads its
    // own wave's writes (lgkmcnt-ordered) -- no extra sync needed.

    if (wv < 2 && lane < 2) {
        float acc = b_out[lane];
        const float* wo = W_out + lane * HSZ;
        #pragma unroll
        for (int j = 0; j < HSZ; ++j) acc += hbuf[wv][0][j] * wo[j];
        out[(2 * bb + wv) * 2 + lane] = acc;
    }
}

extern "C" void kernel_launch(void* const* d_in, const int* in_sizes, int n_in,
                              void* d_out, int out_size, void* d_ws, size_t ws_size,
                              hipStream_t stream) {
    const float* x     = (const float*)d_in[0];
    const float* W_ih  = (const float*)d_in[1];
    const float* W_hh  = (const float*)d_in[2];
    const float* b_ih  = (const float*)d_in[3];
    const float* b_hh  = (const float*)d_in[4];
    const float* W_out = (const float*)d_in[5];
    const float* b_out = (const float*)d_in[6];
    float* out = (float*)d_out;

    const int B = in_sizes[0] / (TSZ * ISZ);   // 512
    hipLaunchKernelGGL(lstm_fused, dim3(B / 2), dim3(256), 0, stream,
                       x, W_ih, W_hh, b_ih, b_hh, W_out, b_out, out);
}